// Round 1
// baseline (1197.385 us; speedup 1.0000x reference)
//
#include <hip/hip_runtime.h>
#include <hip/hip_bf16.h>

namespace {

constexpr int B  = 32;
constexpr int L  = 100;
constexpr int S  = 501;
constexpr int SP = 512;   // padded S
constexpr int DK = 64;
constexpr int DE = 128;

__device__ __forceinline__ float sigm(float x) {
    return __fdividef(1.0f, 1.0f + __expf(-x));
}

// ---------------- precompute: all_learning = concat(e,at,a) @ W1^T + b1 ----
__global__ __launch_bounds__(256) void k_all_learning(
    const int* __restrict__ e_data, const int* __restrict__ a_data,
    const int* __restrict__ at_data,
    const float* __restrict__ e_embed, const float* __restrict__ at_embed,
    const float* __restrict__ W1, const float* __restrict__ b1,
    float* __restrict__ all_learning)
{
    __shared__ float in_s[4][257];
    const int g = threadIdx.x >> 6;
    const int d = threadIdx.x & 63;
    const int row = blockIdx.x * 4 + g;          // grid = 800 -> row < 3200
    const int e  = e_data[row];
    const int at = at_data[row];
    const float a = (float)a_data[row];
    in_s[g][d]        = e_embed[(size_t)e * DE + d];
    in_s[g][64 + d]   = e_embed[(size_t)e * DE + 64 + d];
    in_s[g][128 + d]  = at_embed[(size_t)at * DK + d];
    in_s[g][192 + d]  = a;
    __syncthreads();
    const float* w = W1 + d * 256;
    float acc = b1[d];
    #pragma unroll 8
    for (int k = 0; k < 256; ++k) acc += w[k] * in_s[g][k];
    all_learning[row * DK + d] = acc;
}

// ---------------- precompute: G2,G3 (non-recurrent parts), G4it, pre_y -----
__global__ __launch_bounds__(64) void k_pre_step(
    const int* __restrict__ e_data, const int* __restrict__ it_data,
    const float* __restrict__ e_embed, const float* __restrict__ it_embed,
    const float* __restrict__ all_learning,
    const float* __restrict__ W2, const float* __restrict__ b2,
    const float* __restrict__ W3, const float* __restrict__ b3,
    const float* __restrict__ W4, const float* __restrict__ b4,
    const float* __restrict__ W5, const float* __restrict__ b5,
    float* __restrict__ G2, float* __restrict__ G3,
    float* __restrict__ G4it, float* __restrict__ prey)
{
    __shared__ float lp[64], its[64], ln[64], ee[128];
    const int row = blockIdx.x;                  // b*L + t
    const int t = row % L;
    const int d = threadIdx.x;
    lp[d]  = (t == 0) ? 0.0f : all_learning[(row - 1) * DK + d];
    its[d] = it_embed[(size_t)it_data[row] * DK + d];
    ln[d]  = all_learning[row * DK + d];
    const int e = e_data[row];
    ee[d]      = e_embed[(size_t)e * DE + d];
    ee[64 + d] = e_embed[(size_t)e * DE + 64 + d];
    __syncthreads();
    const float* w2 = W2 + d * 256;
    const float* w3 = W3 + d * 256;
    float g2 = b2[d], g3 = b3[d];
    #pragma unroll 4
    for (int k = 0; k < 64; ++k) {
        g2 += w2[k]       * lp[k];
        g3 += w3[k]       * lp[k];
        g2 += w2[64 + k]  * its[k];
        g3 += w3[64 + k]  * its[k];
        g2 += w2[128 + k] * ln[k];
        g3 += w3[128 + k] * ln[k];
    }
    const float* w4 = W4 + d * 192 + 128;
    float g4 = b4[d];
    #pragma unroll 8
    for (int k = 0; k < 64; ++k) g4 += w4[k] * its[k];
    const float* w5 = W5 + d * 192;
    float py = b5[d];
    #pragma unroll 8
    for (int k = 0; k < 128; ++k) py += w5[k] * ee[k];
    G2[row * DK + d]   = g2;
    G3[row * DK + d]   = g3;
    G4it[row * DK + d] = g4;
    prey[row * DK + d] = py;
}

// ---------------- init: h, ht[0], W4K (transposed W4a), pred[:,0] ----------
__global__ __launch_bounds__(256) void k_init(
    const int* __restrict__ e_data, const float* __restrict__ q_matrix,
    const float* __restrict__ h0, const float* __restrict__ W4,
    float* __restrict__ h, float* __restrict__ ht, float* __restrict__ W4K,
    float* __restrict__ pred)
{
    const int stride = gridDim.x * blockDim.x;
    const int idx = blockIdx.x * blockDim.x + threadIdx.x;
    for (int i = idx; i < B * SP * DK; i += stride) {
        int r = (i >> 6) & (SP - 1);
        int d = i & 63;
        h[i] = (r < S) ? h0[r * DK + d] : 0.0f;
    }
    for (int i = idx; i < B * 8 * DK; i += stride) {
        int d = i & 63;
        int c = (i >> 6) & 7;
        int b = i >> 9;
        float s = 0.0f;
        if (c == 0) {
            const float* q = q_matrix + (size_t)e_data[b * L] * S;
            for (int ss = 0; ss < S; ++ss) s += q[ss] * h0[ss * DK + d];
        }
        ht[i] = s;
    }
    for (int i = idx; i < DK * DK; i += stride) {
        int d = i & 63, k = i >> 6;
        W4K[k * 64 + d] = W4[d * 192 + k];
    }
    for (int i = idx; i < B; i += stride) pred[i * L] = 0.0f;
}

// ---------------- one recurrence step --------------------------------------
// grid (8, B): cx = s-chunk (64 rows), b = batch. block = 256.
__global__ __launch_bounds__(256) void k_step(
    float* __restrict__ h,
    const float* __restrict__ ht_in,     // [B][8][64]  (partials of h_tilde_t)
    float* __restrict__ ht_out,          // [B][8][64]  (partials of h_tilde_{t+1})
    const float* __restrict__ G2, const float* __restrict__ G3,
    const float* __restrict__ G4it,
    const float* __restrict__ W2, const float* __restrict__ W3,
    const float* __restrict__ W4, const float* __restrict__ W4K,
    const float* __restrict__ q_matrix, const int* __restrict__ e_data,
    int t)
{
    __shared__ float hS[64][68];     // h rows (padded: 68*4B = 272B, 16B-aligned, odd*4 bank skew)
    __shared__ float wS[64][68];     // W4a^T, k-major
    __shared__ float HTP[64], LGs[64], Vs[64];
    __shared__ float qeS[64], qnS[64];
    __shared__ float wred[4][64];

    const int tid = threadIdx.x;
    const int cx = blockIdx.x;
    const int b = blockIdx.y;

    // stage h chunk (64x64) and W4K (64x64) via float4
    {
        const float4* hg = (const float4*)(h + ((size_t)b * SP + cx * 64) * DK);
        const float4* wg = (const float4*)W4K;
        #pragma unroll
        for (int p = 0; p < 4; ++p) {
            int i = tid + p * 256;               // i-th float4 of 1024
            int r = i >> 4, k4 = (i & 15) * 4;
            float4 v = hg[i];
            hS[r][k4] = v.x; hS[r][k4 + 1] = v.y; hS[r][k4 + 2] = v.z; hS[r][k4 + 3] = v.w;
            float4 w = wg[i];
            wS[r][k4] = w.x; wS[r][k4 + 1] = w.y; wS[r][k4 + 2] = w.z; wS[r][k4 + 3] = w.w;
        }
    }
    if (tid < 64) {
        float s = 0.0f;
        #pragma unroll
        for (int c = 0; c < 8; ++c) s += ht_in[(b * 8 + c) * DK + tid];
        HTP[tid] = s;
        const int et = e_data[b * L + t];
        const int en = e_data[b * L + t + 1];
        const int ss = cx * 64 + tid;
        float qe = 0.0f, qn = 0.0f;
        if (ss < S) {
            qe = q_matrix[(size_t)et * S + ss];
            qn = q_matrix[(size_t)en * S + ss];
        }
        qeS[tid] = qe; qnS[tid] = qn;
    }
    __syncthreads();
    if (tid < 64) {                               // LG = sig(g3)*(tanh(g2)+1)/2
        const int d = tid;
        float s2 = G2[(b * L + t) * DK + d];
        float s3 = G3[(b * L + t) * DK + d];
        const float* w2 = W2 + d * 256 + 192;
        const float* w3 = W3 + d * 256 + 192;
        #pragma unroll 8
        for (int k = 0; k < 64; ++k) {
            float hp = HTP[k];
            s2 += w2[k] * hp;
            s3 += w3[k] * hp;
        }
        LGs[d] = sigm(s3) * (tanhf(s2) + 1.0f) * 0.5f;
    }
    __syncthreads();
    if (tid < 64) {                               // v = W4b@LG + (W4c@it + b4)
        const int d = tid;
        float v = G4it[(b * L + t) * DK + d];
        const float* w4b = W4 + d * 192 + 64;
        #pragma unroll 8
        for (int k = 0; k < 64; ++k) v += w4b[k] * LGs[k];
        Vs[d] = v;
    }
    __syncthreads();

    // main: 4 rows x 4 d cols per thread; dot over k=64 from LDS
    const int rt = tid >> 4;      // 0..15 -> rows [4rt,4rt+4)
    const int dt = tid & 15;      // 0..15 -> cols [4dt,4dt+4)
    float acc[4][4];
    #pragma unroll
    for (int j = 0; j < 4; ++j)
        #pragma unroll
        for (int i = 0; i < 4; ++i) acc[j][i] = Vs[dt * 4 + i];

    #pragma unroll
    for (int k4 = 0; k4 < 16; ++k4) {
        float hv[4][4], wv[4][4];
        #pragma unroll
        for (int j = 0; j < 4; ++j) {
            float4 th = *(const float4*)&hS[rt * 4 + j][k4 * 4];
            hv[j][0] = th.x; hv[j][1] = th.y; hv[j][2] = th.z; hv[j][3] = th.w;
            float4 tw = *(const float4*)&wS[k4 * 4 + j][dt * 4];
            wv[j][0] = tw.x; wv[j][1] = tw.y; wv[j][2] = tw.z; wv[j][3] = tw.w;
        }
        #pragma unroll
        for (int j = 0; j < 4; ++j)
            #pragma unroll
            for (int kk = 0; kk < 4; ++kk)
                #pragma unroll
                for (int i = 0; i < 4; ++i)
                    acc[j][i] += hv[j][kk] * wv[kk][i];
    }

    float part[4] = {0.f, 0.f, 0.f, 0.f};
    float* hgout = h + ((size_t)b * SP + cx * 64) * DK;
    #pragma unroll
    for (int j = 0; j < 4; ++j) {
        const int r = rt * 4 + j;
        const float qe = qeS[r], qn = qnS[r];
        float4 hold = *(const float4*)&hS[r][dt * 4];
        float hn0 = qe * LGs[dt * 4 + 0] + sigm(acc[j][0]) * hold.x;
        float hn1 = qe * LGs[dt * 4 + 1] + sigm(acc[j][1]) * hold.y;
        float hn2 = qe * LGs[dt * 4 + 2] + sigm(acc[j][2]) * hold.z;
        float hn3 = qe * LGs[dt * 4 + 3] + sigm(acc[j][3]) * hold.w;
        ((float4*)(hgout + (size_t)r * DK))[dt] = make_float4(hn0, hn1, hn2, hn3);
        part[0] += qn * hn0;
        part[1] += qn * hn1;
        part[2] += qn * hn2;
        part[3] += qn * hn3;
    }
    // reduce part over the wave's 4 rt values (lane bits 4..5)
    #pragma unroll
    for (int i = 0; i < 4; ++i) {
        float v = part[i];
        v += __shfl_xor(v, 16);
        v += __shfl_xor(v, 32);
        part[i] = v;
    }
    const int wid = tid >> 6;
    const int lane = tid & 63;
    if (lane < 16) {
        #pragma unroll
        for (int i = 0; i < 4; ++i) wred[wid][lane * 4 + i] = part[i];
    }
    __syncthreads();
    if (tid < 64) {
        ht_out[(b * 8 + cx) * DK + tid] =
            wred[0][tid] + wred[1][tid] + wred[2][tid] + wred[3][tid];
    }
}

// ---------------- epilogue: y_t for t=1..99 --------------------------------
__global__ __launch_bounds__(64) void k_y(
    const float* __restrict__ ht, const float* __restrict__ prey,
    const float* __restrict__ W5, float* __restrict__ pred)
{
    __shared__ float HT[64];
    const int j = blockIdx.x + 1;    // 1..99
    const int b = blockIdx.y;
    const int d = threadIdx.x;
    float s = 0.0f;
    #pragma unroll
    for (int c = 0; c < 8; ++c)
        s += ht[(size_t)j * B * 8 * DK + (b * 8 + c) * DK + d];
    HT[d] = s;
    __syncthreads();
    const float* w5 = W5 + d * 192 + 128;
    float acc = prey[(b * L + j) * DK + d];
    #pragma unroll 8
    for (int k = 0; k < 64; ++k) acc += w5[k] * HT[k];
    float y = sigm(acc);
    #pragma unroll
    for (int m = 1; m < 64; m <<= 1) y += __shfl_xor(y, m);
    if (d == 0) pred[b * L + j] = y * (1.0f / 64.0f);
}

} // namespace

extern "C" void kernel_launch(void* const* d_in, const int* in_sizes, int n_in,
                              void* d_out, int out_size, void* d_ws, size_t ws_size,
                              hipStream_t stream)
{
    const int*   e_data   = (const int*)d_in[0];
    const int*   a_data   = (const int*)d_in[1];
    const int*   at_data  = (const int*)d_in[2];
    const int*   it_data  = (const int*)d_in[3];
    const float* q_matrix = (const float*)d_in[4];
    const float* h0       = (const float*)d_in[5];
    const float* e_embed  = (const float*)d_in[6];
    const float* at_embed = (const float*)d_in[7];
    const float* it_embed = (const float*)d_in[8];
    const float* W1 = (const float*)d_in[9];  const float* b1 = (const float*)d_in[10];
    const float* W2 = (const float*)d_in[11]; const float* b2 = (const float*)d_in[12];
    const float* W3 = (const float*)d_in[13]; const float* b3 = (const float*)d_in[14];
    const float* W4 = (const float*)d_in[15]; const float* b4 = (const float*)d_in[16];
    const float* W5 = (const float*)d_in[17]; const float* b5 = (const float*)d_in[18];
    float* pred = (float*)d_out;

    float* ws   = (float*)d_ws;
    float* h    = ws;                                  // B*SP*DK      = 1,048,576
    float* allL = h    + (size_t)B * SP * DK;          // B*L*DK       =   204,800
    float* G2   = allL + (size_t)B * L * DK;
    float* G3   = G2   + (size_t)B * L * DK;
    float* G4it = G3   + (size_t)B * L * DK;
    float* prey = G4it + (size_t)B * L * DK;
    float* htb  = prey + (size_t)B * L * DK;           // L*B*8*DK     = 1,638,400
    float* W4K  = htb  + (size_t)L * B * 8 * DK;       // 4096
    // total ~14.2 MB of f32 workspace

    hipLaunchKernelGGL(k_all_learning, dim3(B * L / 4), dim3(256), 0, stream,
                       e_data, a_data, at_data, e_embed, at_embed, W1, b1, allL);
    hipLaunchKernelGGL(k_pre_step, dim3(B * L), dim3(64), 0, stream,
                       e_data, it_data, e_embed, it_embed, allL,
                       W2, b2, W3, b3, W4, b4, W5, b5, G2, G3, G4it, prey);
    hipLaunchKernelGGL(k_init, dim3(1024), dim3(256), 0, stream,
                       e_data, q_matrix, h0, W4, h, htb, W4K, pred);
    for (int t = 0; t < L - 1; ++t) {
        hipLaunchKernelGGL(k_step, dim3(8, B), dim3(256), 0, stream,
                           h,
                           htb + (size_t)t * B * 8 * DK,
                           htb + (size_t)(t + 1) * B * 8 * DK,
                           G2, G3, G4it, W2, W3, W4, W4K, q_matrix, e_data, t);
    }
    hipLaunchKernelGGL(k_y, dim3(L - 1, B), dim3(64), 0, stream,
                       htb, prey, W5, pred);
}